// Round 10
// baseline (288.381 us; speedup 1.0000x reference)
//
#include <hip/hip_runtime.h>
#include <hip/hip_bf16.h>

#define NTOT 1048576
#define NSEG 4096
#define HDIM 128
#define ODIM 256
#define BN   64
#define GRID1 256
#define TPB  (NTOT / (BN * GRID1))   // 64 tiles per block
#define NBUF 4

typedef __attribute__((ext_vector_type(8))) short bf16x8;
typedef __attribute__((ext_vector_type(4))) float f32x4;
typedef __attribute__((ext_vector_type(4))) unsigned int u32x4;

typedef const __attribute__((address_space(1))) unsigned int* gp_t;
typedef __attribute__((address_space(3))) unsigned int* lp_t;

// HW packed f32->bf16 RNE (no builtin on gfx950)
__device__ __forceinline__ unsigned int cvt_pk(float lo, float hi) {
    unsigned int r;
    asm("v_cvt_pk_bf16_f32 %0, %1, %2" : "=v"(r) : "v"(lo), "v"(hi));
    return r;
}

// zero sumx (1M floats) + convert W1 (32768 f32 -> 16384 packed u32), one dispatch
__global__ void zero_convert(const float* __restrict__ W1, unsigned int* __restrict__ W1b,
                             float* __restrict__ sumx) {
    int gid = blockIdx.x * 256 + threadIdx.x;
    sumx[gid] = 0.0f;
    if (gid < (ODIM * HDIM / 2)) {
        float2 v = *(const float2*)(W1 + 2 * gid);
        W1b[gid] = cvt_pk(v.x, v.y);
    }
}

// Persistent DMA pipeline, 3 tiles deep (Little's law: >=32KB in flight per CU).
// 512 threads (8 waves x 32 output cols), 4 x 32KB LDS tile buffers, 1 block/CU.
// iter g: {issue 4 DMAs tile g+3 -> buf[(g+3)&3]} vmcnt(12) bar
//         {ds_read frags, cvt_pk, MFMA, tanh, in-reg segreduce+atomics} lgkm(0) bar
__global__ __launch_bounds__(512, 2)
void stage1(const float* __restrict__ x, const int* __restrict__ batch,
            const unsigned short* __restrict__ W1b, const float* __restrict__ b1,
            float* __restrict__ sumx) {
    // fragment-major f32 tiles (R6/R8 layout, HW-verified): 16B chunk b=ks*8+mf*2+half
    // for lane (l15,lhi) lives at LDS chunk b*64+lane (float index chunk*256+lane*4).
    __shared__ __align__(16) float xbuf[NBUF][BN * HDIM];   // 4 x 32 KB
    __shared__ int segAll[TPB * BN];                        // 16 KB

    const int t    = threadIdx.x;
    const int lane = t & 63;
    const int wv   = t >> 6;          // 0..7
    const int l15  = lane & 15;
    const int lhi  = (lane >> 4) & 3;

    // dtype probe: int64 little-endian => odd (high) words are 0
    const bool is64 = (batch[NTOT - 1] == 0);
    const long r0 = (long)blockIdx.x * (TPB * BN);
    const char* xb = (const char*)(x + r0 * HDIM);

    // DMA source byte-offsets within a 32KB tile (pre-permuted global -> fragment-major LDS)
    int doff[4];
    #pragma unroll
    for (int j = 0; j < 4; ++j) {
        int b   = wv * 4 + j;                         // chunk-group 0..31
        int row = ((b >> 1) & 3) * 16 + l15;
        int c4  = (b >> 3) * 8 + lhi * 2 + (b & 1);
        doff[j] = row * 512 + c4 * 16;
    }

    // prologue: issue DMAs for tiles 0,1,2 (96KB in flight immediately)
    #pragma unroll
    for (int tt = 0; tt < 3; ++tt) {
        const char* src = xb + (size_t)tt * (BN * HDIM * 4);
        #pragma unroll
        for (int j = 0; j < 4; ++j)
            __builtin_amdgcn_global_load_lds((gp_t)(src + doff[j]),
                                             (lp_t)(&xbuf[tt][(wv * 4 + j) * 256]), 16, 0, 0);
    }
    __builtin_amdgcn_sched_barrier(0);

    // while DMAs fly: seg table, W1 B-fragments (32 VGPR), bias
    for (int i = t; i < TPB * BN; i += 512) {
        long idx = r0 + i;
        segAll[i] = batch[is64 ? 2 * idx : idx];
    }
    bf16x8 bfr[2][4];   // [nf][ks]; wave wv owns cols [wv*32, wv*32+32)
    #pragma unroll
    for (int nf = 0; nf < 2; ++nf)
        #pragma unroll
        for (int ks = 0; ks < 4; ++ks)
            bfr[nf][ks] = *(const bf16x8*)(W1b + (wv * 32 + nf * 16 + l15) * HDIM + ks * 32 + lhi * 8);
    float bias[2];
    #pragma unroll
    for (int nf = 0; nf < 2; ++nf) bias[nf] = b1[wv * 32 + nf * 16 + l15];

    asm volatile("s_waitcnt lgkmcnt(0)" ::: "memory");   // segAll writes done
    __builtin_amdgcn_sched_barrier(0);
    __builtin_amdgcn_s_barrier();

    for (int g = 0; g < TPB; ++g) {
        // issue prefetch DMAs for tile g+3 into buf freed at end of iter g-1
        if (g + 3 < TPB) {
            const char* src = xb + (size_t)(g + 3) * (BN * HDIM * 4);
            float* dst = &xbuf[(g + 3) & (NBUF - 1)][0];
            #pragma unroll
            for (int j = 0; j < 4; ++j)
                __builtin_amdgcn_global_load_lds((gp_t)(src + doff[j]),
                                                 (lp_t)(dst + (wv * 4 + j) * 256), 16, 0, 0);
            __builtin_amdgcn_sched_barrier(0);
        }
        // counted wait for tile g's DMAs: N = 4 * (#DMA batches issued after tile g's)
        if (g < TPB - 3)       asm volatile("s_waitcnt vmcnt(12)" ::: "memory");
        else if (g == TPB - 3) asm volatile("s_waitcnt vmcnt(8)"  ::: "memory");
        else if (g == TPB - 2) asm volatile("s_waitcnt vmcnt(4)"  ::: "memory");
        else                   asm volatile("s_waitcnt vmcnt(0)"  ::: "memory");
        __builtin_amdgcn_sched_barrier(0);
        __builtin_amdgcn_s_barrier();   // tile g fully in LDS for all waves
        __builtin_amdgcn_sched_barrier(0);

        // ---- compute tile g (pure LDS+VALU+MFMA; no VMEM reads) ----
        f32x4 acc[4][2];
        #pragma unroll
        for (int nf = 0; nf < 2; ++nf) {
            const float bb = bias[nf];
            #pragma unroll
            for (int mf = 0; mf < 4; ++mf)
                acc[mf][nf] = (f32x4){bb, bb, bb, bb};
        }
        const f32x4* fb = (const f32x4*)&xbuf[g & (NBUF - 1)][0];
        #pragma unroll
        for (int ks = 0; ks < 4; ++ks) {
            #pragma unroll
            for (int mf = 0; mf < 4; ++mf) {
                f32x4 u = fb[(ks * 8 + mf * 2) * 64 + lane];       // consecutive lanes: conflict-free
                f32x4 v = fb[(ks * 8 + mf * 2 + 1) * 64 + lane];
                u32x4 w;
                w.x = cvt_pk(u.x, u.y); w.y = cvt_pk(u.z, u.w);
                w.z = cvt_pk(v.x, v.y); w.w = cvt_pk(v.z, v.w);
                bf16x8 af = __builtin_bit_cast(bf16x8, w);
                #pragma unroll
                for (int nf = 0; nf < 2; ++nf)
                    acc[mf][nf] = __builtin_amdgcn_mfma_f32_16x16x32_bf16(af, bfr[nf][ks], acc[mf][nf], 0, 0, 0);
            }
        }

        // tanh(s) = 1 - 2/(1 + 2^(s*2*log2e))
        #pragma unroll
        for (int mf = 0; mf < 4; ++mf)
            #pragma unroll
            for (int nf = 0; nf < 2; ++nf)
                #pragma unroll
                for (int r = 0; r < 4; ++r) {
                    float e = exp2f(acc[mf][nf][r] * 2.885390081777927f);
                    acc[mf][nf][r] = 1.0f - 2.0f * __builtin_amdgcn_rcpf(1.0f + e);
                }

        // in-register segmented reduction (batch sorted); atomics fire-and-forget
        const int* segc = &segAll[g * BN];
        unsigned long long bmask;
        {
            int s_here = segc[lane];
            int s_prev = (lane > 0) ? segc[lane - 1] : s_here;
            bmask = __ballot(s_here != s_prev);
        }
        int start = 0;
        unsigned long long rem = bmask;
        for (;;) {
            const int end = rem ? (int)__builtin_ctzll(rem) : BN;
            const int sid = segc[start];
            float p0 = 0.f, p1 = 0.f;
            #pragma unroll
            for (int mf = 0; mf < 4; ++mf)
                #pragma unroll
                for (int r = 0; r < 4; ++r) {
                    int row = mf * 16 + lhi * 4 + r;
                    float w = ((unsigned)(row - start) < (unsigned)(end - start)) ? 1.0f : 0.0f;
                    p0 = fmaf(w, acc[mf][0][r], p0);
                    p1 = fmaf(w, acc[mf][1][r], p1);
                }
            p0 += __shfl_xor(p0, 16); p0 += __shfl_xor(p0, 32);
            p1 += __shfl_xor(p1, 16); p1 += __shfl_xor(p1, 32);
            if (lhi == 0) {
                float* base = sumx + (long)sid * ODIM + wv * 32 + l15;
                atomicAdd(base +  0, p0);
                atomicAdd(base + 16, p1);
            }
            if (rem == 0) break;
            start = end;
            rem &= rem - 1;
        }

        // my ds_reads of buf[g&3] retired -> buffer reusable for DMA at iter g+1
        asm volatile("s_waitcnt lgkmcnt(0)" ::: "memory");
        __builtin_amdgcn_sched_barrier(0);
        __builtin_amdgcn_s_barrier();
        __builtin_amdgcn_sched_barrier(0);
    }
}

// y[g][h] = b2[h] + sum_o sumx[g][o] * W2[h][o]   (fp32, 268 MFLOP)
__global__ __launch_bounds__(256)
void stage2(const float* __restrict__ sumx, const float* __restrict__ W2,
            const float* __restrict__ b2, float* __restrict__ y) {
    __shared__ float sx[16 * 256];
    const int t = threadIdx.x;
    const long g0 = (long)blockIdx.x * 16;
    #pragma unroll
    for (int i = 0; i < 16; ++i)
        sx[i * 256 + t] = sumx[(g0 + i) * 256 + t];
    __syncthreads();
    const int h = t & 127;
    const int gl0 = (t >> 7) * 8;
    float acc[8] = {0, 0, 0, 0, 0, 0, 0, 0};
    const float* w = W2 + h * 256;
    for (int o4 = 0; o4 < 64; ++o4) {
        float4 wvv = *(const float4*)(w + o4 * 4);
        #pragma unroll
        for (int gl = 0; gl < 8; ++gl) {
            const float* sr = &sx[(gl0 + gl) * 256 + o4 * 4];
            acc[gl] += sr[0] * wvv.x + sr[1] * wvv.y + sr[2] * wvv.z + sr[3] * wvv.w;
        }
    }
    float bb = b2[h];
    #pragma unroll
    for (int gl = 0; gl < 8; ++gl)
        y[(g0 + gl0 + gl) * 128 + h] = acc[gl] + bb;
}

extern "C" void kernel_launch(void* const* d_in, const int* in_sizes, int n_in,
                              void* d_out, int out_size, void* d_ws, size_t ws_size,
                              hipStream_t stream) {
    const float* x   = (const float*)d_in[0];
    const int* batch = (const int*)d_in[1];
    const float* W1  = (const float*)d_in[2];
    const float* b1  = (const float*)d_in[3];
    const float* W2  = (const float*)d_in[4];
    const float* b2  = (const float*)d_in[5];
    float* y = (float*)d_out;

    float* sumx = (float*)d_ws;                                                     // 4 MB
    unsigned short* W1b = (unsigned short*)((char*)d_ws + (size_t)NSEG * ODIM * 4); // 64 KB

    zero_convert<<<dim3(NSEG), dim3(256), 0, stream>>>(W1, (unsigned int*)W1b, sumx);
    stage1<<<dim3(GRID1), dim3(512), 0, stream>>>(x, batch, W1b, b1, sumx);
    stage2<<<dim3(NSEG / 16), dim3(256), 0, stream>>>(sumx, W2, b2, y);
}

// Round 11
// 210.354 us; speedup vs baseline: 1.3709x; 1.3709x over previous
//
#include <hip/hip_runtime.h>
#include <hip/hip_bf16.h>

#define NTOT 1048576
#define NSEG 4096
#define HDIM 128
#define ODIM 256
#define BN   64
#define GRID1 1024
#define TPB  (NTOT / (BN * GRID1))   // 16 tiles per block

typedef __attribute__((ext_vector_type(8))) short bf16x8;
typedef __attribute__((ext_vector_type(4))) float f32x4;
typedef __attribute__((ext_vector_type(4))) unsigned int u32x4;

typedef const __attribute__((address_space(1))) unsigned int* gp_t;
typedef __attribute__((address_space(3))) unsigned int* lp_t;

// HW packed f32->bf16 RNE (no builtin on gfx950)
__device__ __forceinline__ unsigned int cvt_pk(float lo, float hi) {
    unsigned int r;
    asm("v_cvt_pk_bf16_f32 %0, %1, %2" : "=v"(r) : "v"(lo), "v"(hi));
    return r;
}

// zero sumx (1M floats) + convert W1 (32768 f32 -> 16384 packed u32), one dispatch
__global__ void zero_convert(const float* __restrict__ W1, unsigned int* __restrict__ W1b,
                             float* __restrict__ sumx) {
    int gid = blockIdx.x * 256 + threadIdx.x;
    sumx[gid] = 0.0f;
    if (gid < (ODIM * HDIM / 2)) {
        float2 v = *(const float2*)(W1 + 2 * gid);
        W1b[gid] = cvt_pk(v.x, v.y);
    }
}

// R8 structure + line-coalesced DMA: each global_load_lds covers 2 full rows
// (1KB contiguous -> 8 fully-covered 128B lines); the f32->fragment permute is a
// granule XOR *within* each row (source-side swizzle, m173), read back with the
// same XOR (2 lanes/bank = conflict-free). Counted vmcnt keeps prefetch in flight.
__global__ __launch_bounds__(256, 2)
void stage1(const float* __restrict__ x, const int* __restrict__ batch,
            const unsigned short* __restrict__ W1b, const float* __restrict__ b1,
            float* __restrict__ sumx) {
    __shared__ __align__(16) float xbuf[2][BN * HDIM];   // 2 x 32 KB swizzled f32 tiles
    __shared__ int segAll[TPB * BN];                     // 4 KB

    const int t    = threadIdx.x;
    const int lane = t & 63;
    const int wv   = t >> 6;
    const int l15  = lane & 15;
    const int lhi  = (lane >> 4) & 3;

    // dtype probe: int64 little-endian => odd (high) words are 0
    const bool is64 = (batch[NTOT - 1] == 0);
    const long r0 = (long)blockIdx.x * (TPB * BN);
    const char* xb = (const char*)(x + r0 * HDIM);

    // source byte-offsets within a 32KB tile: row-contiguous, granule-XOR-swizzled
    // chunk c = j*256 + wv*64 + lane ; row = c>>5 ; g = c&31
    // src = row*512 + ((g*16) ^ ((row&7)<<4)) ; LDS dest = linear c*16
    int soff[8];
    #pragma unroll
    for (int j = 0; j < 8; ++j) {
        int c = j * 256 + wv * 64 + lane;
        int row = c >> 5, g = c & 31;
        soff[j] = row * 512 + ((g << 4) ^ ((row & 7) << 4));
    }

    // prologue: stage tile 0 (uniform LDS base per instruction; HW adds lane*16)
    #pragma unroll
    for (int j = 0; j < 8; ++j)
        __builtin_amdgcn_global_load_lds((gp_t)(xb + soff[j]),
                                         (lp_t)((char*)&xbuf[0][0] + (j * 256 + wv * 64) * 16), 16, 0, 0);
    __builtin_amdgcn_sched_barrier(0);

    // while DMA flies: seg table, W1 B-fragments (64 VGPR), bias
    for (int i = t; i < TPB * BN; i += 256) {
        long idx = r0 + i;
        segAll[i] = batch[is64 ? 2 * idx : idx];
    }
    bf16x8 bfr[4][4];   // [nf][ks]; wave wv owns cols [wv*64, wv*64+64)
    #pragma unroll
    for (int nf = 0; nf < 4; ++nf)
        #pragma unroll
        for (int ks = 0; ks < 4; ++ks)
            bfr[nf][ks] = *(const bf16x8*)(W1b + (wv * 64 + nf * 16 + l15) * HDIM + ks * 32 + lhi * 8);
    float bias[4];
    #pragma unroll
    for (int nf = 0; nf < 4; ++nf) bias[nf] = b1[wv * 64 + nf * 16 + l15];

    asm volatile("s_waitcnt vmcnt(0) lgkmcnt(0)" ::: "memory");
    __builtin_amdgcn_sched_barrier(0);
    __builtin_amdgcn_s_barrier();

    for (int g = 0; g < TPB; ++g) {
        const int nb = g & 1;

        if (g + 1 < TPB) {
            // issue prefetch DMAs for tile g+1 into the other buffer
            const char* src = xb + (size_t)(g + 1) * (BN * HDIM * 4);
            char* dst = (char*)&xbuf[nb ^ 1][0];
            #pragma unroll
            for (int j = 0; j < 8; ++j)
                __builtin_amdgcn_global_load_lds((gp_t)(src + soff[j]),
                                                 (lp_t)(dst + (j * 256 + wv * 64) * 16), 16, 0, 0);
            __builtin_amdgcn_sched_barrier(0);
            // wait all but the 8 just issued: tile g's DMAs (+older atomics) complete
            asm volatile("s_waitcnt vmcnt(8)" ::: "memory");
        } else {
            asm volatile("s_waitcnt vmcnt(0)" ::: "memory");
        }
        __builtin_amdgcn_sched_barrier(0);
        __builtin_amdgcn_s_barrier();   // bar1: tile g fully in LDS for all waves
        __builtin_amdgcn_sched_barrier(0);

        // ---- compute tile g (pure LDS+VALU+MFMA) ----
        f32x4 acc[4][4];
        #pragma unroll
        for (int nf = 0; nf < 4; ++nf) {
            const float bb = bias[nf];
            #pragma unroll
            for (int mf = 0; mf < 4; ++mf)
                acc[mf][nf] = (f32x4){bb, bb, bb, bb};
        }
        const char* tile = (const char*)&xbuf[nb][0];
        #pragma unroll
        for (int ks = 0; ks < 4; ++ks) {
            #pragma unroll
            for (int mf = 0; mf < 4; ++mf) {
                const int m  = mf * 16 + l15;
                const int rb = m * 512;
                const int kb = ks * 128 + lhi * 32;
                const int sw = (m & 7) << 4;
                f32x4 u = *(const f32x4*)(tile + rb + (kb ^ sw));
                f32x4 v = *(const f32x4*)(tile + rb + ((kb + 16) ^ sw));
                u32x4 w;
                w.x = cvt_pk(u.x, u.y); w.y = cvt_pk(u.z, u.w);
                w.z = cvt_pk(v.x, v.y); w.w = cvt_pk(v.z, v.w);
                bf16x8 af = __builtin_bit_cast(bf16x8, w);
                #pragma unroll
                for (int nf = 0; nf < 4; ++nf)
                    acc[mf][nf] = __builtin_amdgcn_mfma_f32_16x16x32_bf16(af, bfr[nf][ks], acc[mf][nf], 0, 0, 0);
            }
        }

        // tanh(s) = 1 - 2/(1 + 2^(s*2*log2e))
        #pragma unroll
        for (int mf = 0; mf < 4; ++mf)
            #pragma unroll
            for (int nf = 0; nf < 4; ++nf)
                #pragma unroll
                for (int r = 0; r < 4; ++r) {
                    float e = exp2f(acc[mf][nf][r] * 2.885390081777927f);
                    acc[mf][nf][r] = 1.0f - 2.0f * __builtin_amdgcn_rcpf(1.0f + e);
                }

        // in-register segmented reduction (batch sorted); atomics fire-and-forget
        const int* segc = &segAll[g * BN];
        unsigned long long bmask;
        {
            int s_here = segc[lane];
            int s_prev = (lane > 0) ? segc[lane - 1] : s_here;
            bmask = __ballot(s_here != s_prev);
        }
        int start = 0;
        unsigned long long rem = bmask;
        for (;;) {
            const int end = rem ? (int)__builtin_ctzll(rem) : BN;
            const int sid = segc[start];
            float p0 = 0.f, p1 = 0.f, p2 = 0.f, p3 = 0.f;
            #pragma unroll
            for (int mf = 0; mf < 4; ++mf)
                #pragma unroll
                for (int r = 0; r < 4; ++r) {
                    int row = mf * 16 + lhi * 4 + r;
                    float w = ((unsigned)(row - start) < (unsigned)(end - start)) ? 1.0f : 0.0f;
                    p0 = fmaf(w, acc[mf][0][r], p0);
                    p1 = fmaf(w, acc[mf][1][r], p1);
                    p2 = fmaf(w, acc[mf][2][r], p2);
                    p3 = fmaf(w, acc[mf][3][r], p3);
                }
            p0 += __shfl_xor(p0, 16); p0 += __shfl_xor(p0, 32);
            p1 += __shfl_xor(p1, 16); p1 += __shfl_xor(p1, 32);
            p2 += __shfl_xor(p2, 16); p2 += __shfl_xor(p2, 32);
            p3 += __shfl_xor(p3, 16); p3 += __shfl_xor(p3, 32);
            if (lhi == 0) {
                float* base = sumx + (long)sid * ODIM + wv * 64 + l15;
                atomicAdd(base +  0, p0);
                atomicAdd(base + 16, p1);
                atomicAdd(base + 32, p2);
                atomicAdd(base + 48, p3);
            }
            if (rem == 0) break;
            start = end;
            rem &= rem - 1;
        }

        // bar2: my ds_reads of xbuf[nb] retired -> buffer free for next iter's DMA
        asm volatile("s_waitcnt lgkmcnt(0)" ::: "memory");
        __builtin_amdgcn_sched_barrier(0);
        __builtin_amdgcn_s_barrier();
        __builtin_amdgcn_sched_barrier(0);
    }
}

// y[g][h] = b2[h] + sum_o sumx[g][o] * W2[h][o]   (fp32, 268 MFLOP)
__global__ __launch_bounds__(256)
void stage2(const float* __restrict__ sumx, const float* __restrict__ W2,
            const float* __restrict__ b2, float* __restrict__ y) {
    __shared__ float sx[16 * 256];
    const int t = threadIdx.x;
    const long g0 = (long)blockIdx.x * 16;
    #pragma unroll
    for (int i = 0; i < 16; ++i)
        sx[i * 256 + t] = sumx[(g0 + i) * 256 + t];
    __syncthreads();
    const int h = t & 127;
    const int gl0 = (t >> 7) * 8;
    float acc[8] = {0, 0, 0, 0, 0, 0, 0, 0};
    const float* w = W2 + h * 256;
    for (int o4 = 0; o4 < 64; ++o4) {
        float4 wvv = *(const float4*)(w + o4 * 4);
        #pragma unroll
        for (int gl = 0; gl < 8; ++gl) {
            const float* sr = &sx[(gl0 + gl) * 256 + o4 * 4];
            acc[gl] += sr[0] * wvv.x + sr[1] * wvv.y + sr[2] * wvv.z + sr[3] * wvv.w;
        }
    }
    float bb = b2[h];
    #pragma unroll
    for (int gl = 0; gl < 8; ++gl)
        y[(g0 + gl0 + gl) * 128 + h] = acc[gl] + bb;
}

extern "C" void kernel_launch(void* const* d_in, const int* in_sizes, int n_in,
                              void* d_out, int out_size, void* d_ws, size_t ws_size,
                              hipStream_t stream) {
    const float* x   = (const float*)d_in[0];
    const int* batch = (const int*)d_in[1];
    const float* W1  = (const float*)d_in[2];
    const float* b1  = (const float*)d_in[3];
    const float* W2  = (const float*)d_in[4];
    const float* b2  = (const float*)d_in[5];
    float* y = (float*)d_out;

    float* sumx = (float*)d_ws;                                                     // 4 MB
    unsigned short* W1b = (unsigned short*)((char*)d_ws + (size_t)NSEG * ODIM * 4); // 64 KB

    zero_convert<<<dim3(NSEG), dim3(256), 0, stream>>>(W1, (unsigned int*)W1b, sumx);
    stage1<<<dim3(GRID1), dim3(256), 0, stream>>>(x, batch, W1b, b1, sumx);
    stage2<<<dim3(NSEG / 16), dim3(256), 0, stream>>>(sumx, W2, b2, y);
}